// Round 8
// baseline (271.425 us; speedup 1.0000x reference)
//
#include <hip/hip_runtime.h>

// AdapLoss — (8,1,160,160,160) fp32. Memory-bound reduction, 262 MB read.
// R8: deep batch + PLAIN loads, pinned with inline asm.
// History: every plain-load variant (R1/R2/R6/R7) was silently re-serialized
// by the compiler (VGPR 32-36, ~100us, 2.6 TB/s); nt-load variants (R4/R5)
// held 16 loads in flight (~75us, 3.4 TB/s) but nt may bypass L3 and forfeit
// the 131 MB of Infinity-Cache hits that plain loads get (FETCH=131/262 MB).
// Inline asm global_load_dwordx4 + graded manual s_waitcnt = plain cache
// policy AND a held batch. The waitcnt asm ties values via "+v" so consumes
// are data-dependent on it (compiler can't hoist them above the wait).

#define TPB 256
#define BPS 500                            // blocks per sample
constexpr int    F4_PER_SAMPLE = 1024000;  // 160^3 / 4
constexpr int    F4_PER_BLOCK  = 2048;     // 8 float4/thread * 256 threads
constexpr double PER_SAMPLE_D  = 4096000.0;
constexpr float  DELTA = 5.0f;

typedef float vf4 __attribute__((ext_vector_type(4)));

__global__ __launch_bounds__(TPB, 4) void adap_stage1(
    const vf4* __restrict__ pred,
    const vf4* __restrict__ truth,
    float* __restrict__ part)   // [8][BPS][3]
{
    const int s   = blockIdx.y;
    const int b   = blockIdx.x;
    const int tid = threadIdx.x;
    const int base = s * F4_PER_SAMPLE + b * F4_PER_BLOCK + tid;

    // Issue 16 loads back-to-back, interleaved (p0,t0,p1,t1,...).
    // asm volatile: mutual order preserved, compiler can't sink them.
    vf4 p[8], t[8];
    #pragma unroll
    for (int j = 0; j < 8; ++j) {
        const vf4* ap = pred  + (base + j * TPB);
        const vf4* at = truth + (base + j * TPB);
        asm volatile("global_load_dwordx4 %0, %1, off" : "=v"(p[j]) : "v"(ap));
        asm volatile("global_load_dwordx4 %0, %1, off" : "=v"(t[j]) : "v"(at));
    }

    float sum2 = 0.0f, sum1 = 0.0f, sumh = 0.0f;

    // Graded drain: before consuming pair j, allow 14-2j outstanding.
    // The "+v" ties make each consume data-dependent on its waitcnt.
#define CONSUME_PAIR(J, NSTR)                                                   \
    {                                                                           \
        asm volatile("s_waitcnt vmcnt(" NSTR ")" : "+v"(p[J]), "+v"(t[J]));     \
        float e0 = p[J].x - t[J].x, e1 = p[J].y - t[J].y;                       \
        float e2 = p[J].z - t[J].z, e3 = p[J].w - t[J].w;                       \
        float a0 = fabsf(e0), a1 = fabsf(e1), a2 = fabsf(e2), a3 = fabsf(e3);   \
        sum2 += e0*e0 + e1*e1 + e2*e2 + e3*e3;                                  \
        sum1 += a0 + a1 + a2 + a3;                                              \
        float h0 = (a0 <= DELTA) ? 0.5f*e0*e0 : DELTA*(a0 - 0.5f*DELTA);        \
        float h1 = (a1 <= DELTA) ? 0.5f*e1*e1 : DELTA*(a1 - 0.5f*DELTA);        \
        float h2 = (a2 <= DELTA) ? 0.5f*e2*e2 : DELTA*(a2 - 0.5f*DELTA);        \
        float h3 = (a3 <= DELTA) ? 0.5f*e3*e3 : DELTA*(a3 - 0.5f*DELTA);        \
        sumh += h0 + h1 + h2 + h3;                                              \
    }

    CONSUME_PAIR(0, "14")
    CONSUME_PAIR(1, "12")
    CONSUME_PAIR(2, "10")
    CONSUME_PAIR(3, "8")
    CONSUME_PAIR(4, "6")
    CONSUME_PAIR(5, "4")
    CONSUME_PAIR(6, "2")
    CONSUME_PAIR(7, "0")
#undef CONSUME_PAIR

    // wave-64 butterfly reduce
    #pragma unroll
    for (int off = 32; off > 0; off >>= 1) {
        sum2 += __shfl_down(sum2, off, 64);
        sum1 += __shfl_down(sum1, off, 64);
        sumh += __shfl_down(sumh, off, 64);
    }

    __shared__ float w2[4], w1[4], wh[4];
    const int wave = tid >> 6, lane = tid & 63;
    if (lane == 0) { w2[wave] = sum2; w1[wave] = sum1; wh[wave] = sumh; }
    __syncthreads();
    if (tid == 0) {
        float a = 0.f, c = 0.f, h = 0.f;
        #pragma unroll
        for (int w = 0; w < 4; ++w) { a += w2[w]; c += w1[w]; h += wh[w]; }
        const int o = (s * BPS + b) * 3;
        part[o + 0] = a;
        part[o + 1] = c;
        part[o + 2] = h;
    }
}

__global__ __launch_bounds__(TPB) void adap_stage2(
    const float* __restrict__ part,   // [8][BPS][3]
    float* __restrict__ out)
{
    const int tid  = threadIdx.x;
    const int s    = tid >> 5;        // 8 samples x 32 lanes
    const int lane = tid & 31;

    double a = 0.0, b = 0.0, h = 0.0;
    for (int k = lane; k < BPS; k += 32) {
        const float* p = part + (s * BPS + k) * 3;
        a += (double)p[0];
        b += (double)p[1];
        h += (double)p[2];
    }
    #pragma unroll
    for (int off = 16; off > 0; off >>= 1) {
        a += __shfl_down(a, off, 32);
        b += __shfl_down(b, off, 32);
        h += __shfl_down(h, off, 32);
    }

    __shared__ double ps[8];
    if (lane == 0) {
        const double inv = 1.0 / PER_SAMPLE_D;
        double L2 = a * inv, L1 = b * inv, H = h * inv;
        bool use_l2 = (L2 <= 1.0) || (L2 < L1 * L1);
        ps[s] = use_l2 ? L2 : H;
    }
    __syncthreads();
    if (tid == 0) {
        double acc = 0.0;
        #pragma unroll
        for (int i = 0; i < 8; ++i) acc += ps[i];
        out[0] = (float)(acc * 0.125);
    }
}

extern "C" void kernel_launch(void* const* d_in, const int* in_sizes, int n_in,
                              void* d_out, int out_size, void* d_ws, size_t ws_size,
                              hipStream_t stream) {
    const vf4* pred  = (const vf4*)d_in[0];   // y_pred_logits fp32
    const vf4* truth = (const vf4*)d_in[1];   // y_true fp32
    float* part = (float*)d_ws;               // 8*500*3 floats = 48 KB
    float* out  = (float*)d_out;

    dim3 grid1(BPS, 8);
    adap_stage1<<<grid1, TPB, 0, stream>>>(pred, truth, part);
    adap_stage2<<<1, TPB, 0, stream>>>(part, out);
}

// Round 9
// 270.881 us; speedup vs baseline: 1.0020x; 1.0020x over previous
//
#include <hip/hip_runtime.h>

// AdapLoss — (8,1,160,160,160) fp32. Memory-bound reduction, 262 MB read.
// R9: global_load_lds streaming probe. All VGPR-return-path configs cap at
// ~3.4-3.5 TB/s read (R4/R5 deep-nt-batch; ROCm copy = 3.15/direction);
// write path does 6.9 TB/s. Direct-to-LDS DMA bypasses the VGPR return —
// the one untested read path. Wave-private double-buffered LDS (no barrier
// in hot loop -> no m97 barrier-drain), manual graded vmcnt waits.

#define TPB 256
#define BPS 250                              // blocks per sample
constexpr int    FLOATS_PER_SAMPLE = 4096000;   // 160^3
constexpr int    F_PER_BLOCK = 16384;           // floats per input per block
constexpr int    F_PER_WAVE  = 4096;            // floats per input per wave
constexpr int    F_PER_ITER  = 512;             // floats per input per wave-iter (2x 1KB DMA)
constexpr int    ITERS       = 8;
constexpr double PER_SAMPLE_D = 4096000.0;
constexpr float  DELTA = 5.0f;

typedef float vf4 __attribute__((ext_vector_type(4)));
#define AS1 __attribute__((address_space(1)))
#define AS3 __attribute__((address_space(3)))

__global__ __launch_bounds__(TPB, 4) void adap_stage1(
    const float* __restrict__ pred,
    const float* __restrict__ truth,
    float* __restrict__ part)   // [8][BPS][3]
{
    const int s    = blockIdx.y;
    const int b    = blockIdx.x;
    const int tid  = threadIdx.x;
    const int w    = tid >> 6;
    const int lane = tid & 63;

    // [buf][wave][input][512 floats] = 2*4*2*512*4 B = 32 KB
    __shared__ float lds[2][4][2][F_PER_ITER];

    const float* pbase = pred  + s * FLOATS_PER_SAMPLE + b * F_PER_BLOCK + w * F_PER_WAVE;
    const float* tbase = truth + s * FLOATS_PER_SAMPLE + b * F_PER_BLOCK + w * F_PER_WAVE;

    // One DMA instr: 64 lanes x 16 B = 1 KB contiguous; LDS dest is
    // wave-uniform base + lane*16 (m104/m108), matching gp + lane*4 floats.
    auto stage = [&](int bf, int it) {
        const float* gp = pbase + it * F_PER_ITER + lane * 4;
        const float* gt = tbase + it * F_PER_ITER + lane * 4;
        __builtin_amdgcn_global_load_lds((AS1 const void*)gp,         (AS3 void*)&lds[bf][w][0][0],   16, 0, 0);
        __builtin_amdgcn_global_load_lds((AS1 const void*)(gp + 256), (AS3 void*)&lds[bf][w][0][256], 16, 0, 0);
        __builtin_amdgcn_global_load_lds((AS1 const void*)gt,         (AS3 void*)&lds[bf][w][1][0],   16, 0, 0);
        __builtin_amdgcn_global_load_lds((AS1 const void*)(gt + 256), (AS3 void*)&lds[bf][w][1][256], 16, 0, 0);
    };

    float sum2 = 0.0f, sum1 = 0.0f, sumh = 0.0f;

    stage(0, 0);
    #pragma unroll
    for (int it = 0; it < ITERS; ++it) {
        const int bf = it & 1;
        if (it + 1 < ITERS) {
            stage(bf ^ 1, it + 1);                       // prefetch next (4 instrs in flight)
            asm volatile("s_waitcnt vmcnt(4)" ::: "memory");  // current buffer's 4 DMAs done
        } else {
            asm volatile("s_waitcnt vmcnt(0)" ::: "memory");
        }

        const vf4* lp = (const vf4*)&lds[bf][w][0][0];
        const vf4* lt = (const vf4*)&lds[bf][w][1][0];
        vf4 pv[2], tv[2];
        pv[0] = lp[lane]; pv[1] = lp[lane + 64];
        tv[0] = lt[lane]; tv[1] = lt[lane + 64];

        #pragma unroll
        for (int j = 0; j < 2; ++j) {
            float e0 = pv[j].x - tv[j].x, e1 = pv[j].y - tv[j].y;
            float e2 = pv[j].z - tv[j].z, e3 = pv[j].w - tv[j].w;
            float a0 = fabsf(e0), a1 = fabsf(e1), a2 = fabsf(e2), a3 = fabsf(e3);

            sum2 += e0*e0 + e1*e1 + e2*e2 + e3*e3;
            sum1 += a0 + a1 + a2 + a3;

            float h0 = (a0 <= DELTA) ? 0.5f*e0*e0 : DELTA*(a0 - 0.5f*DELTA);
            float h1 = (a1 <= DELTA) ? 0.5f*e1*e1 : DELTA*(a1 - 0.5f*DELTA);
            float h2 = (a2 <= DELTA) ? 0.5f*e2*e2 : DELTA*(a2 - 0.5f*DELTA);
            float h3 = (a3 <= DELTA) ? 0.5f*e3*e3 : DELTA*(a3 - 0.5f*DELTA);
            sumh += h0 + h1 + h2 + h3;
        }
    }

    // wave-64 butterfly reduce
    #pragma unroll
    for (int off = 32; off > 0; off >>= 1) {
        sum2 += __shfl_down(sum2, off, 64);
        sum1 += __shfl_down(sum1, off, 64);
        sumh += __shfl_down(sumh, off, 64);
    }

    __shared__ float w2[4], w1[4], wh[4];
    if (lane == 0) { w2[w] = sum2; w1[w] = sum1; wh[w] = sumh; }
    __syncthreads();
    if (tid == 0) {
        float a = 0.f, c = 0.f, h = 0.f;
        #pragma unroll
        for (int q = 0; q < 4; ++q) { a += w2[q]; c += w1[q]; h += wh[q]; }
        const int o = (s * BPS + b) * 3;
        part[o + 0] = a;
        part[o + 1] = c;
        part[o + 2] = h;
    }
}

__global__ __launch_bounds__(TPB) void adap_stage2(
    const float* __restrict__ part,   // [8][BPS][3]
    float* __restrict__ out)
{
    const int tid  = threadIdx.x;
    const int s    = tid >> 5;        // 8 samples x 32 lanes
    const int lane = tid & 31;

    double a = 0.0, b = 0.0, h = 0.0;
    for (int k = lane; k < BPS; k += 32) {
        const float* p = part + (s * BPS + k) * 3;
        a += (double)p[0];
        b += (double)p[1];
        h += (double)p[2];
    }
    #pragma unroll
    for (int off = 16; off > 0; off >>= 1) {
        a += __shfl_down(a, off, 32);
        b += __shfl_down(b, off, 32);
        h += __shfl_down(h, off, 32);
    }

    __shared__ double ps[8];
    if (lane == 0) {
        const double inv = 1.0 / PER_SAMPLE_D;
        double L2 = a * inv, L1 = b * inv, H = h * inv;
        bool use_l2 = (L2 <= 1.0) || (L2 < L1 * L1);
        ps[s] = use_l2 ? L2 : H;
    }
    __syncthreads();
    if (tid == 0) {
        double acc = 0.0;
        #pragma unroll
        for (int i = 0; i < 8; ++i) acc += ps[i];
        out[0] = (float)(acc * 0.125);
    }
}

extern "C" void kernel_launch(void* const* d_in, const int* in_sizes, int n_in,
                              void* d_out, int out_size, void* d_ws, size_t ws_size,
                              hipStream_t stream) {
    const float* pred  = (const float*)d_in[0];   // y_pred_logits fp32
    const float* truth = (const float*)d_in[1];   // y_true fp32
    float* part = (float*)d_ws;                   // 8*250*3 floats = 24 KB
    float* out  = (float*)d_out;

    dim3 grid1(BPS, 8);
    adap_stage1<<<grid1, TPB, 0, stream>>>(pred, truth, part);
    adap_stage2<<<1, TPB, 0, stream>>>(part, out);
}